// Round 11
// baseline (123.992 us; speedup 1.0000x reference)
//
#include <hip/hip_runtime.h>
#include <math.h>

#define BATCH 16
#define SEQ 64
#define NKEY 196
#define HIDDEN 1024
#define ATT_FEAT 2048
#define EMBED 512
#define MPAD 3200          // feats rows padded to multiple of 128

using short8   = __attribute__((ext_vector_type(8))) short;
using f32x4    = __attribute__((ext_vector_type(4))) float;
using f32x16   = __attribute__((ext_vector_type(16))) float;
using float4v  = __attribute__((ext_vector_type(4))) float;
using uint4v   = __attribute__((ext_vector_type(4))) unsigned;

#define KCONST (-2.8853900817779268f)   // -2*log2(e)
#define LOG2E  (1.4426950408889634f)

// exact truncation split: x = hi + lo + O(2^-16 |x|); bit-ops only
__device__ inline void split8(const float* f, short8& hi, short8& lo) {
    uint4v hp, lp;
    #pragma unroll
    for (int p = 0; p < 4; ++p) {
        unsigned u0 = __builtin_bit_cast(unsigned, f[2 * p + 0]);
        unsigned u1 = __builtin_bit_cast(unsigned, f[2 * p + 1]);
        unsigned m0 = u0 & 0xFFFF0000u;
        unsigned m1 = u1 & 0xFFFF0000u;
        hp[p] = m1 | (u0 >> 16);
        float l0 = f[2 * p + 0] - __builtin_bit_cast(float, m0);
        float l1 = f[2 * p + 1] - __builtin_bit_cast(float, m1);
        unsigned v0 = __builtin_bit_cast(unsigned, l0);
        unsigned v1 = __builtin_bit_cast(unsigned, l1);
        lp[p] = (v1 & 0xFFFF0000u) | (v0 >> 16);
    }
    hi = __builtin_bit_cast(short8, hp);
    lo = __builtin_bit_cast(short8, lp);
}

// async global->LDS, 16B per lane; dest = uniform base + lane*16
__device__ __forceinline__ void gl_lds16(const unsigned short* g, unsigned short* l) {
    __builtin_amdgcn_global_load_lds(
        (const __attribute__((address_space(1))) unsigned int*)g,
        (__attribute__((address_space(3))) unsigned int*)l, 16, 0, 0);
}

// ---------------------------------------------------------------------------
// Tiled images: per (row-tile 128, k-tile 32): [s(2)][kh(2)][row(128)][8 bf16]
// = 4096 elems (8 KB). Image order: tile-major rows, then k.
// ---------------------------------------------------------------------------
__device__ inline void prep_a128(
    const float* __restrict__ A, unsigned short* __restrict__ Th,
    unsigned short* __restrict__ Tl, int K, int Mreal, int tm, int tk, int t)
{
    const int r    = t >> 1;            // 0..127
    const int half = t & 1;             // 32-k half of the 64-k chunk
    const int grow = tm * 128 + r;
    float f[32];
    if (grow < Mreal) {
        const float* src = A + (size_t)grow * K + tk * 64 + half * 32;
        #pragma unroll
        for (int q = 0; q < 8; ++q) {
            float4v v = *(const float4v*)(src + q * 4);
            f[q*4+0] = v.x; f[q*4+1] = v.y; f[q*4+2] = v.z; f[q*4+3] = v.w;
        }
    } else {
        #pragma unroll
        for (int j = 0; j < 32; ++j) f[j] = 0.f;
    }
    const int tkk = tk * 2 + half;
    const size_t base = ((size_t)tm * (K >> 5) + tkk) * 4096;
    #pragma unroll
    for (int s = 0; s < 2; ++s)
        #pragma unroll
        for (int kh = 0; kh < 2; ++kh) {
            short8 hi, lo;
            split8(f + s * 16 + kh * 8, hi, lo);
            size_t off = base + (size_t)((s * 2 + kh) * 128 + r) * 8;
            *(short8*)(Th + off) = hi;
            *(short8*)(Tl + off) = lo;
        }
}

__device__ inline void prep_b128(
    const float* __restrict__ W, unsigned short* __restrict__ Th,
    unsigned short* __restrict__ Tl, int K, int N, int tn, int tk, int t,
    float (*tile)[129])
{
    {
        const int kr = t >> 2;              // 0..63
        const int nc = (t & 3) * 32;
        const float* src = W + (size_t)(tk * 64 + kr) * N + tn * 128 + nc;
        #pragma unroll
        for (int q = 0; q < 8; ++q) {
            float4v v = *(const float4v*)(src + q * 4);
            tile[kr][nc + q*4 + 0] = v.x; tile[kr][nc + q*4 + 1] = v.y;
            tile[kr][nc + q*4 + 2] = v.z; tile[kr][nc + q*4 + 3] = v.w;
        }
    }
    __syncthreads();
    {
        const int c    = t >> 1;            // 0..127
        const int half = t & 1;
        const int tkk  = tk * 2 + half;
        const size_t base = ((size_t)tn * (K >> 5) + tkk) * 4096;
        #pragma unroll
        for (int s = 0; s < 2; ++s)
            #pragma unroll
            for (int kh = 0; kh < 2; ++kh) {
                float f[8];
                #pragma unroll
                for (int j = 0; j < 8; ++j)
                    f[j] = tile[half * 32 + s * 16 + kh * 8 + j][c];
                short8 hi, lo;
                split8(f, hi, lo);
                size_t off = base + (size_t)((s * 2 + kh) * 128 + c) * 8;
                *(short8*)(Th + off) = hi;
                *(short8*)(Tl + off) = lo;
            }
    }
}

// one dispatch for all four preps (1120 blocks)
__global__ __launch_bounds__(256) void uber_prep(
    const float* __restrict__ hidden, const float* __restrict__ feats,
    const float* __restrict__ w_h, const float* __restrict__ w_u,
    unsigned short* HAh, unsigned short* HAl,
    unsigned short* FAh, unsigned short* FAl,
    unsigned short* HBh, unsigned short* HBl,
    unsigned short* UBh, unsigned short* UBl)
{
    __shared__ float tile[64][129];
    const int id = blockIdx.x;
    const int t  = threadIdx.x;
    if (id < 128) {                                   // hidden A: 8 x 16
        prep_a128(hidden, HAh, HAl, HIDDEN, BATCH * SEQ, id >> 4, id & 15, t);
    } else if (id < 928) {                            // feats A: 25 x 32
        const int j = id - 128;
        prep_a128(feats, FAh, FAl, ATT_FEAT, BATCH * NKEY, j >> 5, j & 31, t);
    } else if (id < 992) {                            // w_h B: 4 x 16
        const int j = id - 928;
        prep_b128(w_h, HBh, HBl, HIDDEN, EMBED, j >> 4, j & 15, t, tile);
    } else {                                          // w_u B: 4 x 32
        const int j = id - 992;
        prep_b128(w_u, UBh, UBl, ATT_FEAT, EMBED, j >> 5, j & 31, t, tile);
    }
}

// ---------------------------------------------------------------------------
// uber GEMM v2: 128x128 block, BK=32, 4 waves in 2x2, each wave 64x64
// (2x2 frags of 32x32x16). Split-bf16 3-product. Staging global_load_lds w16,
// counted vmcnt(8). Grid 132 = K1 32 (8x4) + K2 100 (25x4), bijective XCD
// swizzle (q=16, r=4). Epilogue pre-scales by KCONST and folds bias.
// ---------------------------------------------------------------------------
__global__ __launch_bounds__(256) void uber_gemm(
    const unsigned short* __restrict__ HAh, const unsigned short* __restrict__ HAl,
    const unsigned short* __restrict__ HBh, const unsigned short* __restrict__ HBl,
    const unsigned short* __restrict__ FAh, const unsigned short* __restrict__ FAl,
    const unsigned short* __restrict__ UBh, const unsigned short* __restrict__ UBl,
    const float* __restrict__ bvec, float* __restrict__ Wh, float* __restrict__ Uv)
{
    __shared__ __align__(16) unsigned short L[4][2][4096];   // 64 KB

    const int hh  = blockIdx.x;
    const int xcd = hh & 7, idx = hh >> 3;
    const int t0  = (xcd < 4) ? xcd * 17 + idx : 68 + (xcd - 4) * 16 + idx;

    const unsigned short *Ah, *Al, *Bh, *Bl;
    const float* bias;
    float* C;
    int ktiles, rt, ct;
    if (t0 < 32) {             // K1: Wh = hidden @ w_h
        Ah = HAh; Al = HAl; Bh = HBh; Bl = HBl;
        bias = nullptr; C = Wh; ktiles = HIDDEN >> 5;
        rt = t0 >> 2; ct = t0 & 3;
    } else {                   // K2: Uv = feats @ w_u + b
        const int u = t0 - 32;
        Ah = FAh; Al = FAl; Bh = UBh; Bl = UBl;
        bias = bvec; C = Uv; ktiles = ATT_FEAT >> 5;
        rt = u >> 2; ct = u & 3;
    }

    const int tid = threadIdx.x, lane = tid & 63, w = tid >> 6;
    const int wr = w >> 1, wc = w & 1;
    const int l31 = lane & 31, kh = lane >> 5;

    const unsigned short* srcMat = (w == 0) ? Ah : (w == 1) ? Al : (w == 2) ? Bh : Bl;
    const int majorTile = (w < 2) ? rt : ct;
    const unsigned short* src0 = srcMat + (size_t)majorTile * ktiles * 4096 + lane * 8;

    f32x16 acc[2][2] = {};

    auto stage = [&](int buf, int t) {
        const unsigned short* s = src0 + (size_t)t * 4096;
        unsigned short* d = &L[w][buf][0];
        #pragma unroll
        for (int c = 0; c < 8; ++c)
            gl_lds16(s + c * 512, d + c * 512);
    };

    auto compute = [&](int buf) {
        #pragma unroll
        for (int s = 0; s < 2; ++s) {
            const int rb = (s * 2 + kh) * 128;
            short8 ah[2], al[2], bh[2], bl[2];
            #pragma unroll
            for (int m = 0; m < 2; ++m) {
                const int off = (rb + wr * 64 + m * 32 + l31) * 8;
                ah[m] = *(const short8*)&L[0][buf][off];
                al[m] = *(const short8*)&L[1][buf][off];
            }
            #pragma unroll
            for (int n = 0; n < 2; ++n) {
                const int off = (rb + wc * 64 + n * 32 + l31) * 8;
                bh[n] = *(const short8*)&L[2][buf][off];
                bl[n] = *(const short8*)&L[3][buf][off];
            }
            #pragma unroll
            for (int m = 0; m < 2; ++m)
                #pragma unroll
                for (int n = 0; n < 2; ++n) {
                    acc[m][n] = __builtin_amdgcn_mfma_f32_32x32x16_bf16(ah[m], bh[n], acc[m][n], 0, 0, 0);
                    acc[m][n] = __builtin_amdgcn_mfma_f32_32x32x16_bf16(ah[m], bl[n], acc[m][n], 0, 0, 0);
                    acc[m][n] = __builtin_amdgcn_mfma_f32_32x32x16_bf16(al[m], bh[n], acc[m][n], 0, 0, 0);
                }
        }
    };

    stage(0, 0);
    for (int t = 0; t < ktiles; ++t) {
        const int cur = t & 1;
        if (t + 1 < ktiles) {
            stage(cur ^ 1, t + 1);
            asm volatile("s_waitcnt vmcnt(8)" ::: "memory");
        } else {
            asm volatile("s_waitcnt vmcnt(0)" ::: "memory");
        }
        __builtin_amdgcn_s_barrier();
        __builtin_amdgcn_sched_barrier(0);
        compute(cur);
        __builtin_amdgcn_sched_barrier(0);
        __builtin_amdgcn_s_barrier();
    }

    // epilogue: frag layout col=lane&31, row=(r&3)+8*(r>>2)+4*kh; scale by KC
    #pragma unroll
    for (int m = 0; m < 2; ++m) {
        const int row0 = rt * 128 + wr * 64 + m * 32;
        #pragma unroll
        for (int n = 0; n < 2; ++n) {
            const int colg = ct * 128 + wc * 64 + n * 32 + l31;
            const float bv = bias ? bias[colg] : 0.f;
            #pragma unroll
            for (int r = 0; r < 16; ++r) {
                const int row = (r & 3) + 8 * (r >> 2) + 4 * kh;
                C[(size_t)(row0 + row) * EMBED + colg] = (acc[m][n][r] + bv) * KCONST;
            }
        }
    }
}

// ---------------------------------------------------------------------------
// scores[b,s,n] = 2 * sum_e w[e] / (1 + exp2(Wh'+Uv'))   (inputs pre-scaled
// by KC, bias folded); mask==0 -> -1e9. Writes to scratch (d_ws).
// ---------------------------------------------------------------------------
__global__ __launch_bounds__(256) void scores_kernel(
    const float* __restrict__ Wh, const float* __restrict__ Uv,
    const float* __restrict__ wvec, const int* __restrict__ mask,
    float* __restrict__ scores)
{
    const int n0 = blockIdx.x * 16;
    const int s0 = blockIdx.y * 16;
    const int b  = blockIdx.z;
    const int tid = threadIdx.x;
    const int tx = tid & 15;
    const int ty = tid >> 4;

    __shared__ float whs[16][64];
    __shared__ float uvs[16][64];

    const int r  = tid >> 4;
    const int c4 = tid & 15;
    const int sr = s0 + r;
    const int nr_raw = n0 + r;
    const int nr = nr_raw < NKEY ? nr_raw : NKEY - 1;

    const float* WhRow = Wh + (size_t)(b * SEQ + sr) * EMBED;
    const float* UvRow = Uv + (size_t)(b * NKEY + nr) * EMBED;

    float acc0 = 0.f, acc1 = 0.f, acc2 = 0.f, acc3 = 0.f;

    for (int e0 = 0; e0 < EMBED; e0 += 64) {
        float4v wv = *(const float4v*)(WhRow + e0 + c4 * 4);
        float4v uv = *(const float4v*)(UvRow + e0 + c4 * 4);
        *(float4v*)&whs[r][(c4 ^ r) << 2] = wv;
        *(float4v*)&uvs[r][(c4 ^ r) << 2] = uv;
        __syncthreads();

        #pragma unroll
        for (int c = 0; c < 16; ++c) {
            float4v whv = *(const float4v*)&whs[ty][(c ^ ty) << 2];
            float4v uvv = *(const float4v*)&uvs[tx][(c ^ tx) << 2];
            const float w0 = wvec[e0 + c * 4 + 0];
            const float w1 = wvec[e0 + c * 4 + 1];
            const float w2 = wvec[e0 + c * 4 + 2];
            const float w3 = wvec[e0 + c * 4 + 3];
            float t0 = __builtin_amdgcn_exp2f(whv.x + uvv.x);
            float t1 = __builtin_amdgcn_exp2f(whv.y + uvv.y);
            float t2 = __builtin_amdgcn_exp2f(whv.z + uvv.z);
            float t3 = __builtin_amdgcn_exp2f(whv.w + uvv.w);
            acc0 = fmaf(w0, __builtin_amdgcn_rcpf(1.f + t0), acc0);
            acc1 = fmaf(w1, __builtin_amdgcn_rcpf(1.f + t1), acc1);
            acc2 = fmaf(w2, __builtin_amdgcn_rcpf(1.f + t2), acc2);
            acc3 = fmaf(w3, __builtin_amdgcn_rcpf(1.f + t3), acc3);
        }
        __syncthreads();
    }

    float sc = 2.f * ((acc0 + acc1) + (acc2 + acc3));
    const int n = n0 + tx;
    if (n < NKEY) {
        float v = (mask[b * NKEY + n] == 0) ? -1e9f : sc;
        scores[(size_t)(b * SEQ + s0 + ty) * NKEY + n] = v;
    }
}

// ---------------------------------------------------------------------------
// attn + softmax fused: block covers 8 s-rows x full N for one b.
// Grid (2, 8, 16).
// ---------------------------------------------------------------------------
__global__ __launch_bounds__(256) void attn_softmax_kernel(
    const float* __restrict__ scores, const float* __restrict__ feats,
    float* __restrict__ weights_out, float* __restrict__ out)
{
    const int t   = threadIdx.x;
    const int fb  = blockIdx.x;
    const int s0  = blockIdx.y * 8;
    const int b   = blockIdx.z;

    __shared__ float wt[NKEY][8];   // wt[n][s]

    // ---- softmax: row r handled by 32 lanes ----
    {
        const int r  = t >> 5;          // 0..7
        const int ln = t & 31;
        const float* srow = scores + (size_t)(b * SEQ + s0 + r) * NKEY;
        float v[7];
        float mx = -INFINITY;
        #pragma unroll
        for (int j = 0; j < 7; ++j) {
            const int n = ln + 32 * j;
            v[j] = (n < NKEY) ? srow[n] : -INFINITY;
            mx = fmaxf(mx, v[j]);
        }
        #pragma unroll
        for (int off = 16; off; off >>= 1) mx = fmaxf(mx, __shfl_xor(mx, off));
        float sum = 0.f;
        #pragma unroll
        for (int j = 0; j < 7; ++j) {
            v[j] = __builtin_amdgcn_exp2f((v[j] - mx) * LOG2E);
            if (ln + 32 * j < NKEY) sum += v[j];
        }
        #pragma unroll
        for (int off = 16; off; off >>= 1) sum += __shfl_xor(sum, off);
        const float inv = __builtin_amdgcn_rcpf(sum);
        float* wrow = weights_out + (size_t)(b * SEQ + s0 + r) * NKEY;
        #pragma unroll
        for (int j = 0; j < 7; ++j) {
            const int n = ln + 32 * j;
            if (n < NKEY) {
                const float wv = v[j] * inv;
                wt[n][r] = wv;
                if (fb == 0) wrow[n] = wv;
            }
        }
    }
    __syncthreads();

    // ---- attn ----
    const int col = fb * 1024 + t * 4;
    const float* fp = feats + (size_t)b * NKEY * ATT_FEAT + col;

    float4v acc[8] = {};
    #pragma unroll 4
    for (int n = 0; n < NKEY; ++n) {
        float4v f  = *(const float4v*)(fp + (size_t)n * ATT_FEAT);
        float4v w0 = *(const float4v*)&wt[n][0];
        float4v w1 = *(const float4v*)&wt[n][4];
        acc[0] += w0.x * f;
        acc[1] += w0.y * f;
        acc[2] += w0.z * f;
        acc[3] += w0.w * f;
        acc[4] += w1.x * f;
        acc[5] += w1.y * f;
        acc[6] += w1.z * f;
        acc[7] += w1.w * f;
    }

    float* op = out + (size_t)(b * SEQ + s0) * ATT_FEAT + col;
    #pragma unroll
    for (int s = 0; s < 8; ++s)
        *(float4v*)(op + (size_t)s * ATT_FEAT) = acc[s];
}

// ---------------------------------------------------------------------------
extern "C" void kernel_launch(void* const* d_in, const int* in_sizes, int n_in,
                              void* d_out, int out_size, void* d_ws, size_t ws_size,
                              hipStream_t stream)
{
    const float* hidden = (const float*)d_in[0];
    const float* feats  = (const float*)d_in[1];
    const int*   mask   = (const int*)  d_in[2];
    const float* w_h    = (const float*)d_in[3];
    const float* w_u    = (const float*)d_in[4];
    const float* bvec   = (const float*)d_in[5];
    const float* wvec   = (const float*)d_in[6];

    float* out         = (float*)d_out;
    float* attn_out    = out;
    float* weights_out = out + (size_t)BATCH * SEQ * ATT_FEAT;

    // workspace layout (~46 MB)
    float* Wh  = (float*)d_ws;                                   // 1024x512
    float* Uv  = Wh + (size_t)BATCH * SEQ * EMBED;               // 3200x512
    float* scr = Uv + (size_t)MPAD * EMBED;                      // raw scores
    unsigned short* FAh = (unsigned short*)(scr + (size_t)BATCH * SEQ * NKEY);
    unsigned short* FAl = FAh + (size_t)MPAD * ATT_FEAT;         // 25x64 imgs
    unsigned short* HAh = FAl + (size_t)MPAD * ATT_FEAT;
    unsigned short* HAl = HAh + (size_t)BATCH * SEQ * HIDDEN;    // 8x32 imgs
    unsigned short* UBh = HAl + (size_t)BATCH * SEQ * HIDDEN;
    unsigned short* UBl = UBh + (size_t)EMBED * ATT_FEAT;        // 4x64 imgs
    unsigned short* HBh = UBl + (size_t)EMBED * ATT_FEAT;
    unsigned short* HBl = HBh + (size_t)EMBED * HIDDEN;          // 4x32 imgs

    // 1) all preps (1120 blocks)
    uber_prep<<<dim3(1120), 256, 0, stream>>>(
        hidden, feats, w_h, w_u, HAh, HAl, FAh, FAl, HBh, HBl, UBh, UBl);

    // 2) both GEMMs (132 blocks), outputs pre-scaled by KC, bias folded
    uber_gemm<<<dim3(132), 256, 0, stream>>>(
        HAh, HAl, HBh, HBl, FAh, FAl, UBh, UBl, bvec, Wh, Uv);

    // 3) scores (+mask) -> scratch
    scores_kernel<<<dim3((NKEY + 15) / 16, SEQ / 16, BATCH), 256, 0, stream>>>(
        Wh, Uv, wvec, mask, scr);

    // 4) softmax + weights write + attn
    attn_softmax_kernel<<<dim3(ATT_FEAT / 1024, SEQ / 8, BATCH), 256, 0, stream>>>(
        scr, feats, weights_out, attn_out);
}

// Round 12
// 107.150 us; speedup vs baseline: 1.1572x; 1.1572x over previous
//
#include <hip/hip_runtime.h>
#include <math.h>

#define BATCH 16
#define SEQ 64
#define NKEY 196
#define HIDDEN 1024
#define ATT_FEAT 2048
#define EMBED 512
#define MPAD 3200          // feats rows padded to multiple of 128

using short8   = __attribute__((ext_vector_type(8))) short;
using f32x4    = __attribute__((ext_vector_type(4))) float;
using f32x16   = __attribute__((ext_vector_type(16))) float;
using float4v  = __attribute__((ext_vector_type(4))) float;
using uint4v   = __attribute__((ext_vector_type(4))) unsigned;

#define KCONST (-2.8853900817779268f)   // -2*log2(e)
#define LOG2E  (1.4426950408889634f)

// exact truncation split: x = hi + lo + O(2^-16 |x|); bit-ops only
__device__ inline void split8(const float* f, short8& hi, short8& lo) {
    uint4v hp, lp;
    #pragma unroll
    for (int p = 0; p < 4; ++p) {
        unsigned u0 = __builtin_bit_cast(unsigned, f[2 * p + 0]);
        unsigned u1 = __builtin_bit_cast(unsigned, f[2 * p + 1]);
        unsigned m0 = u0 & 0xFFFF0000u;
        unsigned m1 = u1 & 0xFFFF0000u;
        hp[p] = m1 | (u0 >> 16);
        float l0 = f[2 * p + 0] - __builtin_bit_cast(float, m0);
        float l1 = f[2 * p + 1] - __builtin_bit_cast(float, m1);
        unsigned v0 = __builtin_bit_cast(unsigned, l0);
        unsigned v1 = __builtin_bit_cast(unsigned, l1);
        lp[p] = (v1 & 0xFFFF0000u) | (v0 >> 16);
    }
    hi = __builtin_bit_cast(short8, hp);
    lo = __builtin_bit_cast(short8, lp);
}

// async global->LDS, 16B per lane; dest = uniform base + lane*16
__device__ __forceinline__ void gl_lds16(const unsigned short* g, unsigned short* l) {
    __builtin_amdgcn_global_load_lds(
        (const __attribute__((address_space(1))) unsigned int*)g,
        (__attribute__((address_space(3))) unsigned int*)l, 16, 0, 0);
}

// ---------------------------------------------------------------------------
// Tiled images: per (row-tile 128, k-tile 32): [s(2)][kh(2)][row(128)][8 bf16]
// = 4096 elems (8 KB). Image order: tile-major rows, then k.
// ---------------------------------------------------------------------------
__device__ inline void prep_a128(
    const float* __restrict__ A, unsigned short* __restrict__ Th,
    unsigned short* __restrict__ Tl, int K, int Mreal, int tm, int tk, int t)
{
    const int r    = t >> 1;            // 0..127
    const int half = t & 1;             // 32-k half of the 64-k chunk
    const int grow = tm * 128 + r;
    float f[32];
    if (grow < Mreal) {
        const float* src = A + (size_t)grow * K + tk * 64 + half * 32;
        #pragma unroll
        for (int q = 0; q < 8; ++q) {
            float4v v = *(const float4v*)(src + q * 4);
            f[q*4+0] = v.x; f[q*4+1] = v.y; f[q*4+2] = v.z; f[q*4+3] = v.w;
        }
    } else {
        #pragma unroll
        for (int j = 0; j < 32; ++j) f[j] = 0.f;
    }
    const int tkk = tk * 2 + half;
    const size_t base = ((size_t)tm * (K >> 5) + tkk) * 4096;
    #pragma unroll
    for (int s = 0; s < 2; ++s)
        #pragma unroll
        for (int kh = 0; kh < 2; ++kh) {
            short8 hi, lo;
            split8(f + s * 16 + kh * 8, hi, lo);
            size_t off = base + (size_t)((s * 2 + kh) * 128 + r) * 8;
            *(short8*)(Th + off) = hi;
            *(short8*)(Tl + off) = lo;
        }
}

__device__ inline void prep_b128(
    const float* __restrict__ W, unsigned short* __restrict__ Th,
    unsigned short* __restrict__ Tl, int K, int N, int tn, int tk, int t,
    float (*tile)[129])
{
    {
        const int kr = t >> 2;              // 0..63
        const int nc = (t & 3) * 32;
        const float* src = W + (size_t)(tk * 64 + kr) * N + tn * 128 + nc;
        #pragma unroll
        for (int q = 0; q < 8; ++q) {
            float4v v = *(const float4v*)(src + q * 4);
            tile[kr][nc + q*4 + 0] = v.x; tile[kr][nc + q*4 + 1] = v.y;
            tile[kr][nc + q*4 + 2] = v.z; tile[kr][nc + q*4 + 3] = v.w;
        }
    }
    __syncthreads();
    {
        const int c    = t >> 1;            // 0..127
        const int half = t & 1;
        const int tkk  = tk * 2 + half;
        const size_t base = ((size_t)tn * (K >> 5) + tkk) * 4096;
        #pragma unroll
        for (int s = 0; s < 2; ++s)
            #pragma unroll
            for (int kh = 0; kh < 2; ++kh) {
                float f[8];
                #pragma unroll
                for (int j = 0; j < 8; ++j)
                    f[j] = tile[half * 32 + s * 16 + kh * 8 + j][c];
                short8 hi, lo;
                split8(f, hi, lo);
                size_t off = base + (size_t)((s * 2 + kh) * 128 + c) * 8;
                *(short8*)(Th + off) = hi;
                *(short8*)(Tl + off) = lo;
            }
    }
}

// one dispatch for all four preps (1120 blocks)
__global__ __launch_bounds__(256) void uber_prep(
    const float* __restrict__ hidden, const float* __restrict__ feats,
    const float* __restrict__ w_h, const float* __restrict__ w_u,
    unsigned short* HAh, unsigned short* HAl,
    unsigned short* FAh, unsigned short* FAl,
    unsigned short* HBh, unsigned short* HBl,
    unsigned short* UBh, unsigned short* UBl)
{
    __shared__ float tile[64][129];
    const int id = blockIdx.x;
    const int t  = threadIdx.x;
    if (id < 128) {                                   // hidden A: 8 x 16
        prep_a128(hidden, HAh, HAl, HIDDEN, BATCH * SEQ, id >> 4, id & 15, t);
    } else if (id < 928) {                            // feats A: 25 x 32
        const int j = id - 128;
        prep_a128(feats, FAh, FAl, ATT_FEAT, BATCH * NKEY, j >> 5, j & 31, t);
    } else if (id < 992) {                            // w_h B: 4 x 16
        const int j = id - 928;
        prep_b128(w_h, HBh, HBl, HIDDEN, EMBED, j >> 4, j & 15, t, tile);
    } else {                                          // w_u B: 4 x 32
        const int j = id - 992;
        prep_b128(w_u, UBh, UBl, ATT_FEAT, EMBED, j >> 5, j & 31, t, tile);
    }
}

// ---------------------------------------------------------------------------
// uber GEMM v3 (k-split): 128x128 tile, 4 waves in 2x2, each wave 64x64,
// BK=32, every block does exactly 16 k-steps.
//   K2 (Uv): 25rt x 4ct x 4ks = 400 blocks -> 4 f32 partial buffers
//   K1 (Wh):  8rt x 4ct x 2ks =  64 blocks -> 2 f32 partial buffers
// Grid 464 = 8*58, bijective XCD swizzle. Staging global_load_lds w16,
// counted vmcnt(8). Epilogue scales by KCONST; bias folded into partial 0.
// scores_kernel sums the partials.
// ---------------------------------------------------------------------------
__global__ __launch_bounds__(256) void uber_gemm(
    const unsigned short* __restrict__ HAh, const unsigned short* __restrict__ HAl,
    const unsigned short* __restrict__ HBh, const unsigned short* __restrict__ HBl,
    const unsigned short* __restrict__ FAh, const unsigned short* __restrict__ FAl,
    const unsigned short* __restrict__ UBh, const unsigned short* __restrict__ UBl,
    const float* __restrict__ bvec, float* __restrict__ WhP, float* __restrict__ UvP)
{
    __shared__ __align__(16) unsigned short L[4][2][4096];   // 64 KB

    const int hh = blockIdx.x;
    const int t0 = (hh & 7) * 58 + (hh >> 3);                // bijective, G=464

    const unsigned short *Ah, *Al, *Bh, *Bl;
    const float* bias = nullptr;
    float* C;
    int rt, ct, tk0, aK;
    if (t0 < 400) {            // K2: Uv partials
        const int u = t0;
        const int ks = u / 100, rem = u % 100;
        rt = rem >> 2; ct = rem & 3;
        Ah = FAh; Al = FAl; Bh = UBh; Bl = UBl;
        aK = ATT_FEAT >> 5; tk0 = ks * 16;
        C = UvP + (size_t)ks * MPAD * EMBED;
        if (ks == 0) bias = bvec;
    } else {                   // K1: Wh partials
        const int v = t0 - 400;
        const int ks = v >> 5, rem = v & 31;
        rt = rem >> 2; ct = rem & 3;
        Ah = HAh; Al = HAl; Bh = HBh; Bl = HBl;
        aK = HIDDEN >> 5; tk0 = ks * 16;
        C = WhP + (size_t)ks * (BATCH * SEQ) * EMBED;
    }

    const int tid = threadIdx.x, lane = tid & 63, w = tid >> 6;
    const int wr = w >> 1, wc = w & 1;
    const int l31 = lane & 31, kh = lane >> 5;

    const unsigned short* srcMat = (w == 0) ? Ah : (w == 1) ? Al : (w == 2) ? Bh : Bl;
    const int majorTile = (w < 2) ? rt : ct;
    const unsigned short* src0 =
        srcMat + ((size_t)majorTile * aK + tk0) * 4096 + lane * 8;

    f32x16 acc[2][2] = {};

    auto stage = [&](int buf, int t) {
        const unsigned short* s = src0 + (size_t)t * 4096;
        unsigned short* d = &L[w][buf][0];
        #pragma unroll
        for (int c = 0; c < 8; ++c)
            gl_lds16(s + c * 512, d + c * 512);
    };

    auto compute = [&](int buf) {
        #pragma unroll
        for (int s = 0; s < 2; ++s) {
            const int rb = (s * 2 + kh) * 128;
            short8 ah[2], al[2], bh[2], bl[2];
            #pragma unroll
            for (int m = 0; m < 2; ++m) {
                const int off = (rb + wr * 64 + m * 32 + l31) * 8;
                ah[m] = *(const short8*)&L[0][buf][off];
                al[m] = *(const short8*)&L[1][buf][off];
            }
            #pragma unroll
            for (int n = 0; n < 2; ++n) {
                const int off = (rb + wc * 64 + n * 32 + l31) * 8;
                bh[n] = *(const short8*)&L[2][buf][off];
                bl[n] = *(const short8*)&L[3][buf][off];
            }
            __builtin_amdgcn_s_setprio(1);
            #pragma unroll
            for (int m = 0; m < 2; ++m)
                #pragma unroll
                for (int n = 0; n < 2; ++n) {
                    acc[m][n] = __builtin_amdgcn_mfma_f32_32x32x16_bf16(ah[m], bh[n], acc[m][n], 0, 0, 0);
                    acc[m][n] = __builtin_amdgcn_mfma_f32_32x32x16_bf16(ah[m], bl[n], acc[m][n], 0, 0, 0);
                    acc[m][n] = __builtin_amdgcn_mfma_f32_32x32x16_bf16(al[m], bh[n], acc[m][n], 0, 0, 0);
                }
            __builtin_amdgcn_s_setprio(0);
        }
    };

    stage(0, 0);
    #pragma unroll 1
    for (int t = 0; t < 16; ++t) {
        const int cur = t & 1;
        if (t + 1 < 16) {
            stage(cur ^ 1, t + 1);
            asm volatile("s_waitcnt vmcnt(8)" ::: "memory");
        } else {
            asm volatile("s_waitcnt vmcnt(0)" ::: "memory");
        }
        __builtin_amdgcn_s_barrier();
        __builtin_amdgcn_sched_barrier(0);
        compute(cur);
        __builtin_amdgcn_sched_barrier(0);
        __builtin_amdgcn_s_barrier();
    }

    // epilogue: frag layout col=lane&31, row=(r&3)+8*(r>>2)+4*kh; scale by KC
    #pragma unroll
    for (int m = 0; m < 2; ++m) {
        const int row0 = rt * 128 + wr * 64 + m * 32;
        #pragma unroll
        for (int n = 0; n < 2; ++n) {
            const int colg = ct * 128 + wc * 64 + n * 32 + l31;
            const float bv = bias ? bias[colg] : 0.f;
            #pragma unroll
            for (int r = 0; r < 16; ++r) {
                const int row = (r & 3) + 8 * (r >> 2) + 4 * kh;
                C[(size_t)(row0 + row) * EMBED + colg] = (acc[m][n][r] + bv) * KCONST;
            }
        }
    }
}

// ---------------------------------------------------------------------------
// scores[b,s,n] = 2 * sum_e w[e] / (1 + exp2(sum_p Wh_p + sum_p Uv_p))
// Partials summed during LDS staging. mask==0 -> -1e9. Writes scratch.
// ---------------------------------------------------------------------------
__global__ __launch_bounds__(256) void scores_kernel(
    const float* __restrict__ WhP, const float* __restrict__ UvP,
    const float* __restrict__ wvec, const int* __restrict__ mask,
    float* __restrict__ scores)
{
    const int n0 = blockIdx.x * 16;
    const int s0 = blockIdx.y * 16;
    const int b  = blockIdx.z;
    const int tid = threadIdx.x;
    const int tx = tid & 15;
    const int ty = tid >> 4;

    __shared__ float whs[16][64];
    __shared__ float uvs[16][64];

    const int r  = tid >> 4;
    const int c4 = tid & 15;
    const int sr = s0 + r;
    const int nr_raw = n0 + r;
    const int nr = nr_raw < NKEY ? nr_raw : NKEY - 1;

    const size_t WHS = (size_t)(BATCH * SEQ) * EMBED;
    const size_t UVS = (size_t)MPAD * EMBED;
    const float* WhRow = WhP + (size_t)(b * SEQ + sr) * EMBED;
    const float* UvRow = UvP + (size_t)(b * NKEY + nr) * EMBED;

    float acc0 = 0.f, acc1 = 0.f, acc2 = 0.f, acc3 = 0.f;

    for (int e0 = 0; e0 < EMBED; e0 += 64) {
        const int off = e0 + c4 * 4;
        float4v wv = *(const float4v*)(WhRow + off)
                   + *(const float4v*)(WhRow + WHS + off);
        float4v uv = *(const float4v*)(UvRow + off)
                   + *(const float4v*)(UvRow + UVS + off)
                   + *(const float4v*)(UvRow + 2 * UVS + off)
                   + *(const float4v*)(UvRow + 3 * UVS + off);
        *(float4v*)&whs[r][(c4 ^ r) << 2] = wv;
        *(float4v*)&uvs[r][(c4 ^ r) << 2] = uv;
        __syncthreads();

        #pragma unroll
        for (int c = 0; c < 16; ++c) {
            float4v whv = *(const float4v*)&whs[ty][(c ^ ty) << 2];
            float4v uvv = *(const float4v*)&uvs[tx][(c ^ tx) << 2];
            const float w0 = wvec[e0 + c * 4 + 0];
            const float w1 = wvec[e0 + c * 4 + 1];
            const float w2 = wvec[e0 + c * 4 + 2];
            const float w3 = wvec[e0 + c * 4 + 3];
            float t0 = __builtin_amdgcn_exp2f(whv.x + uvv.x);
            float t1 = __builtin_amdgcn_exp2f(whv.y + uvv.y);
            float t2 = __builtin_amdgcn_exp2f(whv.z + uvv.z);
            float t3 = __builtin_amdgcn_exp2f(whv.w + uvv.w);
            acc0 = fmaf(w0, __builtin_amdgcn_rcpf(1.f + t0), acc0);
            acc1 = fmaf(w1, __builtin_amdgcn_rcpf(1.f + t1), acc1);
            acc2 = fmaf(w2, __builtin_amdgcn_rcpf(1.f + t2), acc2);
            acc3 = fmaf(w3, __builtin_amdgcn_rcpf(1.f + t3), acc3);
        }
        __syncthreads();
    }

    float sc = 2.f * ((acc0 + acc1) + (acc2 + acc3));
    const int n = n0 + tx;
    if (n < NKEY) {
        float v = (mask[b * NKEY + n] == 0) ? -1e9f : sc;
        scores[(size_t)(b * SEQ + s0 + ty) * NKEY + n] = v;
    }
}

// ---------------------------------------------------------------------------
// attn + softmax fused: block covers 8 s-rows x full N for one b.
// Grid (2, 8, 16).
// ---------------------------------------------------------------------------
__global__ __launch_bounds__(256) void attn_softmax_kernel(
    const float* __restrict__ scores, const float* __restrict__ feats,
    float* __restrict__ weights_out, float* __restrict__ out)
{
    const int t   = threadIdx.x;
    const int fb  = blockIdx.x;
    const int s0  = blockIdx.y * 8;
    const int b   = blockIdx.z;

    __shared__ float wt[NKEY][8];   // wt[n][s]

    // ---- softmax: row r handled by 32 lanes ----
    {
        const int r  = t >> 5;          // 0..7
        const int ln = t & 31;
        const float* srow = scores + (size_t)(b * SEQ + s0 + r) * NKEY;
        float v[7];
        float mx = -INFINITY;
        #pragma unroll
        for (int j = 0; j < 7; ++j) {
            const int n = ln + 32 * j;
            v[j] = (n < NKEY) ? srow[n] : -INFINITY;
            mx = fmaxf(mx, v[j]);
        }
        #pragma unroll
        for (int off = 16; off; off >>= 1) mx = fmaxf(mx, __shfl_xor(mx, off));
        float sum = 0.f;
        #pragma unroll
        for (int j = 0; j < 7; ++j) {
            v[j] = __builtin_amdgcn_exp2f((v[j] - mx) * LOG2E);
            if (ln + 32 * j < NKEY) sum += v[j];
        }
        #pragma unroll
        for (int off = 16; off; off >>= 1) sum += __shfl_xor(sum, off);
        const float inv = __builtin_amdgcn_rcpf(sum);
        float* wrow = weights_out + (size_t)(b * SEQ + s0 + r) * NKEY;
        #pragma unroll
        for (int j = 0; j < 7; ++j) {
            const int n = ln + 32 * j;
            if (n < NKEY) {
                const float wv = v[j] * inv;
                wt[n][r] = wv;
                if (fb == 0) wrow[n] = wv;
            }
        }
    }
    __syncthreads();

    // ---- attn ----
    const int col = fb * 1024 + t * 4;
    const float* fp = feats + (size_t)b * NKEY * ATT_FEAT + col;

    float4v acc[8] = {};
    #pragma unroll 4
    for (int n = 0; n < NKEY; ++n) {
        float4v f  = *(const float4v*)(fp + (size_t)n * ATT_FEAT);
        float4v w0 = *(const float4v*)&wt[n][0];
        float4v w1 = *(const float4v*)&wt[n][4];
        acc[0] += w0.x * f;
        acc[1] += w0.y * f;
        acc[2] += w0.z * f;
        acc[3] += w0.w * f;
        acc[4] += w1.x * f;
        acc[5] += w1.y * f;
        acc[6] += w1.z * f;
        acc[7] += w1.w * f;
    }

    float* op = out + (size_t)(b * SEQ + s0) * ATT_FEAT + col;
    #pragma unroll
    for (int s = 0; s < 8; ++s)
        *(float4v*)(op + (size_t)s * ATT_FEAT) = acc[s];
}

// ---------------------------------------------------------------------------
extern "C" void kernel_launch(void* const* d_in, const int* in_sizes, int n_in,
                              void* d_out, int out_size, void* d_ws, size_t ws_size,
                              hipStream_t stream)
{
    const float* hidden = (const float*)d_in[0];
    const float* feats  = (const float*)d_in[1];
    const int*   mask   = (const int*)  d_in[2];
    const float* w_h    = (const float*)d_in[3];
    const float* w_u    = (const float*)d_in[4];
    const float* bvec   = (const float*)d_in[5];
    const float* wvec   = (const float*)d_in[6];

    float* out         = (float*)d_out;
    float* attn_out    = out;
    float* weights_out = out + (size_t)BATCH * SEQ * ATT_FEAT;

    // workspace layout (~68 MB)
    float* WhP = (float*)d_ws;                                   // 2 x 1024x512
    float* UvP = WhP + (size_t)2 * BATCH * SEQ * EMBED;          // 4 x 3200x512
    float* scr = UvP + (size_t)4 * MPAD * EMBED;                 // raw scores
    unsigned short* FAh = (unsigned short*)(scr + (size_t)BATCH * SEQ * NKEY);
    unsigned short* FAl = FAh + (size_t)MPAD * ATT_FEAT;         // feats imgs
    unsigned short* HAh = FAl + (size_t)MPAD * ATT_FEAT;
    unsigned short* HAl = HAh + (size_t)BATCH * SEQ * HIDDEN;    // hidden imgs
    unsigned short* UBh = HAl + (size_t)BATCH * SEQ * HIDDEN;
    unsigned short* UBl = UBh + (size_t)EMBED * ATT_FEAT;        // w_u imgs
    unsigned short* HBh = UBl + (size_t)EMBED * ATT_FEAT;
    unsigned short* HBl = HBh + (size_t)EMBED * HIDDEN;          // w_h imgs

    // 1) all preps (1120 blocks)
    uber_prep<<<dim3(1120), 256, 0, stream>>>(
        hidden, feats, w_h, w_u, HAh, HAl, FAh, FAl, HBh, HBl, UBh, UBl);

    // 2) both GEMMs k-split (464 blocks), partial outputs pre-scaled by KC
    uber_gemm<<<dim3(464), 256, 0, stream>>>(
        HAh, HAl, HBh, HBl, FAh, FAl, UBh, UBl, bvec, WhP, UvP);

    // 3) scores (+partial reduce, +mask) -> scratch
    scores_kernel<<<dim3((NKEY + 15) / 16, SEQ / 16, BATCH), 256, 0, stream>>>(
        WhP, UvP, wvec, mask, scr);

    // 4) softmax + weights write + attn
    attn_softmax_kernel<<<dim3(ATT_FEAT / 1024, SEQ / 8, BATCH), 256, 0, stream>>>(
        scr, feats, weights_out, attn_out);
}

// Round 13
// 102.275 us; speedup vs baseline: 1.2123x; 1.0477x over previous
//
#include <hip/hip_runtime.h>
#include <math.h>

#define BATCH 16
#define SEQ 64
#define NKEY 196
#define HIDDEN 1024
#define ATT_FEAT 2048
#define EMBED 512
#define MPAD 3200          // feats rows padded to multiple of 128

using short8   = __attribute__((ext_vector_type(8))) short;
using f32x4    = __attribute__((ext_vector_type(4))) float;
using f32x16   = __attribute__((ext_vector_type(16))) float;
using float4v  = __attribute__((ext_vector_type(4))) float;
using uint4v   = __attribute__((ext_vector_type(4))) unsigned;

#define KCONST (-2.8853900817779268f)   // -2*log2(e)
#define LOG2E  (1.4426950408889634f)

// exact truncation split: x = hi + lo + O(2^-16 |x|); bit-ops only
__device__ inline void split8(const float* f, short8& hi, short8& lo) {
    uint4v hp, lp;
    #pragma unroll
    for (int p = 0; p < 4; ++p) {
        unsigned u0 = __builtin_bit_cast(unsigned, f[2 * p + 0]);
        unsigned u1 = __builtin_bit_cast(unsigned, f[2 * p + 1]);
        unsigned m0 = u0 & 0xFFFF0000u;
        unsigned m1 = u1 & 0xFFFF0000u;
        hp[p] = m1 | (u0 >> 16);
        float l0 = f[2 * p + 0] - __builtin_bit_cast(float, m0);
        float l1 = f[2 * p + 1] - __builtin_bit_cast(float, m1);
        unsigned v0 = __builtin_bit_cast(unsigned, l0);
        unsigned v1 = __builtin_bit_cast(unsigned, l1);
        lp[p] = (v1 & 0xFFFF0000u) | (v0 >> 16);
    }
    hi = __builtin_bit_cast(short8, hp);
    lo = __builtin_bit_cast(short8, lp);
}

// async global->LDS, 16B per lane; dest = uniform base + lane*16
__device__ __forceinline__ void gl_lds16(const unsigned short* g, unsigned short* l) {
    __builtin_amdgcn_global_load_lds(
        (const __attribute__((address_space(1))) unsigned int*)g,
        (__attribute__((address_space(3))) unsigned int*)l, 16, 0, 0);
}

// ---------------------------------------------------------------------------
// Tiled images: per (row-tile 128, k-tile 32): [s(2)][kh(2)][row(128)][8 bf16]
// ---------------------------------------------------------------------------
__device__ inline void prep_a128(
    const float* __restrict__ A, unsigned short* __restrict__ Th,
    unsigned short* __restrict__ Tl, int K, int Mreal, int tm, int tk, int t)
{
    const int r    = t >> 1;
    const int half = t & 1;
    const int grow = tm * 128 + r;
    float f[32];
    if (grow < Mreal) {
        const float* src = A + (size_t)grow * K + tk * 64 + half * 32;
        #pragma unroll
        for (int q = 0; q < 8; ++q) {
            float4v v = *(const float4v*)(src + q * 4);
            f[q*4+0] = v.x; f[q*4+1] = v.y; f[q*4+2] = v.z; f[q*4+3] = v.w;
        }
    } else {
        #pragma unroll
        for (int j = 0; j < 32; ++j) f[j] = 0.f;
    }
    const int tkk = tk * 2 + half;
    const size_t base = ((size_t)tm * (K >> 5) + tkk) * 4096;
    #pragma unroll
    for (int s = 0; s < 2; ++s)
        #pragma unroll
        for (int kh = 0; kh < 2; ++kh) {
            short8 hi, lo;
            split8(f + s * 16 + kh * 8, hi, lo);
            size_t off = base + (size_t)((s * 2 + kh) * 128 + r) * 8;
            *(short8*)(Th + off) = hi;
            *(short8*)(Tl + off) = lo;
        }
}

__device__ inline void prep_b128(
    const float* __restrict__ W, unsigned short* __restrict__ Th,
    unsigned short* __restrict__ Tl, int K, int N, int tn, int tk, int t,
    float (*tile)[129])
{
    {
        const int kr = t >> 2;
        const int nc = (t & 3) * 32;
        const float* src = W + (size_t)(tk * 64 + kr) * N + tn * 128 + nc;
        #pragma unroll
        for (int q = 0; q < 8; ++q) {
            float4v v = *(const float4v*)(src + q * 4);
            tile[kr][nc + q*4 + 0] = v.x; tile[kr][nc + q*4 + 1] = v.y;
            tile[kr][nc + q*4 + 2] = v.z; tile[kr][nc + q*4 + 3] = v.w;
        }
    }
    __syncthreads();
    {
        const int c    = t >> 1;
        const int half = t & 1;
        const int tkk  = tk * 2 + half;
        const size_t base = ((size_t)tn * (K >> 5) + tkk) * 4096;
        #pragma unroll
        for (int s = 0; s < 2; ++s)
            #pragma unroll
            for (int kh = 0; kh < 2; ++kh) {
                float f[8];
                #pragma unroll
                for (int j = 0; j < 8; ++j)
                    f[j] = tile[half * 32 + s * 16 + kh * 8 + j][c];
                short8 hi, lo;
                split8(f, hi, lo);
                size_t off = base + (size_t)((s * 2 + kh) * 128 + c) * 8;
                *(short8*)(Th + off) = hi;
                *(short8*)(Tl + off) = lo;
            }
    }
}

__global__ __launch_bounds__(256) void uber_prep(
    const float* __restrict__ hidden, const float* __restrict__ feats,
    const float* __restrict__ w_h, const float* __restrict__ w_u,
    unsigned short* HAh, unsigned short* HAl,
    unsigned short* FAh, unsigned short* FAl,
    unsigned short* HBh, unsigned short* HBl,
    unsigned short* UBh, unsigned short* UBl)
{
    __shared__ float tile[64][129];
    const int id = blockIdx.x;
    const int t  = threadIdx.x;
    if (id < 128) {
        prep_a128(hidden, HAh, HAl, HIDDEN, BATCH * SEQ, id >> 4, id & 15, t);
    } else if (id < 928) {
        const int j = id - 128;
        prep_a128(feats, FAh, FAl, ATT_FEAT, BATCH * NKEY, j >> 5, j & 31, t);
    } else if (id < 992) {
        const int j = id - 928;
        prep_b128(w_h, HBh, HBl, HIDDEN, EMBED, j >> 4, j & 15, t, tile);
    } else {
        const int j = id - 992;
        prep_b128(w_u, UBh, UBl, ATT_FEAT, EMBED, j >> 5, j & 31, t, tile);
    }
}

// ---------------------------------------------------------------------------
// uber GEMM (k-split): 128x128 tile, 4 waves 2x2, wave 64x64, BK=32,
// 16 k-steps per block. K2 400 blocks (4 partials), K1 64 blocks (2 partials).
// Grid 464 = 8*58 bijective XCD swizzle. Epilogue scales by KCONST, bias in p0.
// ---------------------------------------------------------------------------
__global__ __launch_bounds__(256) void uber_gemm(
    const unsigned short* __restrict__ HAh, const unsigned short* __restrict__ HAl,
    const unsigned short* __restrict__ HBh, const unsigned short* __restrict__ HBl,
    const unsigned short* __restrict__ FAh, const unsigned short* __restrict__ FAl,
    const unsigned short* __restrict__ UBh, const unsigned short* __restrict__ UBl,
    const float* __restrict__ bvec, float* __restrict__ WhP, float* __restrict__ UvP)
{
    __shared__ __align__(16) unsigned short L[4][2][4096];   // 64 KB

    const int hh = blockIdx.x;
    const int t0 = (hh & 7) * 58 + (hh >> 3);                // bijective, G=464

    const unsigned short *Ah, *Al, *Bh, *Bl;
    const float* bias = nullptr;
    float* C;
    int rt, ct, tk0, aK;
    if (t0 < 400) {            // K2: Uv partials
        const int u = t0;
        const int ks = u / 100, rem = u % 100;
        rt = rem >> 2; ct = rem & 3;
        Ah = FAh; Al = FAl; Bh = UBh; Bl = UBl;
        aK = ATT_FEAT >> 5; tk0 = ks * 16;
        C = UvP + (size_t)ks * MPAD * EMBED;
        if (ks == 0) bias = bvec;
    } else {                   // K1: Wh partials
        const int v = t0 - 400;
        const int ks = v >> 5, rem = v & 31;
        rt = rem >> 2; ct = rem & 3;
        Ah = HAh; Al = HAl; Bh = HBh; Bl = HBl;
        aK = HIDDEN >> 5; tk0 = ks * 16;
        C = WhP + (size_t)ks * (BATCH * SEQ) * EMBED;
    }

    const int tid = threadIdx.x, lane = tid & 63, w = tid >> 6;
    const int wr = w >> 1, wc = w & 1;
    const int l31 = lane & 31, kh = lane >> 5;

    const unsigned short* srcMat = (w == 0) ? Ah : (w == 1) ? Al : (w == 2) ? Bh : Bl;
    const int majorTile = (w < 2) ? rt : ct;
    const unsigned short* src0 =
        srcMat + ((size_t)majorTile * aK + tk0) * 4096 + lane * 8;

    f32x16 acc[2][2] = {};

    auto stage = [&](int buf, int t) {
        const unsigned short* s = src0 + (size_t)t * 4096;
        unsigned short* d = &L[w][buf][0];
        #pragma unroll
        for (int c = 0; c < 8; ++c)
            gl_lds16(s + c * 512, d + c * 512);
    };

    auto compute = [&](int buf) {
        #pragma unroll
        for (int s = 0; s < 2; ++s) {
            const int rb = (s * 2 + kh) * 128;
            short8 ah[2], al[2], bh[2], bl[2];
            #pragma unroll
            for (int m = 0; m < 2; ++m) {
                const int off = (rb + wr * 64 + m * 32 + l31) * 8;
                ah[m] = *(const short8*)&L[0][buf][off];
                al[m] = *(const short8*)&L[1][buf][off];
            }
            #pragma unroll
            for (int n = 0; n < 2; ++n) {
                const int off = (rb + wc * 64 + n * 32 + l31) * 8;
                bh[n] = *(const short8*)&L[2][buf][off];
                bl[n] = *(const short8*)&L[3][buf][off];
            }
            __builtin_amdgcn_s_setprio(1);
            #pragma unroll
            for (int m = 0; m < 2; ++m)
                #pragma unroll
                for (int n = 0; n < 2; ++n) {
                    acc[m][n] = __builtin_amdgcn_mfma_f32_32x32x16_bf16(ah[m], bh[n], acc[m][n], 0, 0, 0);
                    acc[m][n] = __builtin_amdgcn_mfma_f32_32x32x16_bf16(ah[m], bl[n], acc[m][n], 0, 0, 0);
                    acc[m][n] = __builtin_amdgcn_mfma_f32_32x32x16_bf16(al[m], bh[n], acc[m][n], 0, 0, 0);
                }
            __builtin_amdgcn_s_setprio(0);
        }
    };

    stage(0, 0);
    #pragma unroll 1
    for (int t = 0; t < 16; ++t) {
        const int cur = t & 1;
        if (t + 1 < 16) {
            stage(cur ^ 1, t + 1);
            asm volatile("s_waitcnt vmcnt(8)" ::: "memory");
        } else {
            asm volatile("s_waitcnt vmcnt(0)" ::: "memory");
        }
        __builtin_amdgcn_s_barrier();
        __builtin_amdgcn_sched_barrier(0);
        compute(cur);
        __builtin_amdgcn_sched_barrier(0);
        __builtin_amdgcn_s_barrier();
    }

    #pragma unroll
    for (int m = 0; m < 2; ++m) {
        const int row0 = rt * 128 + wr * 64 + m * 32;
        #pragma unroll
        for (int n = 0; n < 2; ++n) {
            const int colg = ct * 128 + wc * 64 + n * 32 + l31;
            const float bv = bias ? bias[colg] : 0.f;
            #pragma unroll
            for (int r = 0; r < 16; ++r) {
                const int row = (r & 3) + 8 * (r >> 2) + 4 * kh;
                C[(size_t)(row0 + row) * EMBED + colg] = (acc[m][n][r] + bv) * KCONST;
            }
        }
    }
}

// ---------------------------------------------------------------------------
// scores v3: partial scores over an e-quarter (128 e).
//   scr4[eq][b*64+s][n] = 2 * sum_{e in quarter} w[e]/(1+exp2(Wh'+Uv'))
// Block: 64 s x 16 n x 128 e, 4 waves (wave = 4 n, lane = s).
// wh chunk kept in regs, reused across the wave's 4 n; uv reads broadcast.
// Partial (2x Wh, 4x Uv) reduction folded into staging. No mask here.
// Grid (13, 4, 16).
// ---------------------------------------------------------------------------
__global__ __launch_bounds__(256) void scores4_kernel(
    const float* __restrict__ WhP, const float* __restrict__ UvP,
    const float* __restrict__ wvec, float* __restrict__ scr4)
{
    const int n0 = blockIdx.x * 16;
    const int eq = blockIdx.y;
    const int b  = blockIdx.z;
    const int tid = threadIdx.x;
    const int w    = tid >> 6;
    const int lane = tid & 63;         // = s

    __shared__ float whs[64 * 64];     // swizzled, 16 KB
    __shared__ float uvs[16][64];      // plain (broadcast reads)

    const size_t WHS = (size_t)(BATCH * SEQ) * EMBED;
    const size_t UVS = (size_t)MPAD * EMBED;

    float acc[4] = {};
    char* whsB = (char*)whs;

    for (int ch = 0; ch < 2; ++ch) {
        const int e0 = eq * 128 + ch * 64;
        // ---- stage whs[64 s][64 e] with 2-partial reduce, XOR-swizzled ----
        {
            const int r = tid >> 2;
            const float* Wr = WhP + (size_t)(b * SEQ + r) * EMBED + e0;
            #pragma unroll
            for (int q = 0; q < 4; ++q) {
                const int cc = (tid & 3) * 16 + q * 4;
                float4v v = *(const float4v*)(Wr + cc)
                          + *(const float4v*)(Wr + WHS + cc);
                *(float4v*)(whsB + r * 256 + ((cc * 4) ^ ((r & 15) << 4))) = v;
            }
        }
        // ---- stage uvs[16 n][64 e] with 4-partial reduce ----
        {
            const int nl = tid >> 4;
            const int c4 = tid & 15;
            const int nr = (n0 + nl < NKEY) ? (n0 + nl) : (NKEY - 1);
            const float* Ur = UvP + (size_t)(b * NKEY + nr) * EMBED + e0 + c4 * 4;
            float4v u = *(const float4v*)(Ur)
                      + *(const float4v*)(Ur + UVS)
                      + *(const float4v*)(Ur + 2 * UVS)
                      + *(const float4v*)(Ur + 3 * UVS);
            *(float4v*)&uvs[nl][c4 * 4] = u;
        }
        __syncthreads();

        // ---- compute: 8 chunks of 8 e ----
        #pragma unroll
        for (int ec = 0; ec < 8; ++ec) {
            const int sb = lane * 256;
            float4v wh0 = *(const float4v*)(whsB + sb + ((ec * 32 +  0) ^ ((lane & 15) << 4)));
            float4v wh1 = *(const float4v*)(whsB + sb + ((ec * 32 + 16) ^ ((lane & 15) << 4)));
            float wf[8];
            #pragma unroll
            for (int i = 0; i < 8; ++i) wf[i] = wvec[e0 + ec * 8 + i];
            #pragma unroll
            for (int j = 0; j < 4; ++j) {
                const int nl = w * 4 + j;
                float4v u0 = *(const float4v*)&uvs[nl][ec * 8];
                float4v u1 = *(const float4v*)&uvs[nl][ec * 8 + 4];
                float t0 = __builtin_amdgcn_exp2f(wh0.x + u0.x);
                float t1 = __builtin_amdgcn_exp2f(wh0.y + u0.y);
                float t2 = __builtin_amdgcn_exp2f(wh0.z + u0.z);
                float t3 = __builtin_amdgcn_exp2f(wh0.w + u0.w);
                float t4 = __builtin_amdgcn_exp2f(wh1.x + u1.x);
                float t5 = __builtin_amdgcn_exp2f(wh1.y + u1.y);
                float t6 = __builtin_amdgcn_exp2f(wh1.z + u1.z);
                float t7 = __builtin_amdgcn_exp2f(wh1.w + u1.w);
                float a = acc[j];
                a = fmaf(wf[0], __builtin_amdgcn_rcpf(1.f + t0), a);
                a = fmaf(wf[1], __builtin_amdgcn_rcpf(1.f + t1), a);
                a = fmaf(wf[2], __builtin_amdgcn_rcpf(1.f + t2), a);
                a = fmaf(wf[3], __builtin_amdgcn_rcpf(1.f + t3), a);
                a = fmaf(wf[4], __builtin_amdgcn_rcpf(1.f + t4), a);
                a = fmaf(wf[5], __builtin_amdgcn_rcpf(1.f + t5), a);
                a = fmaf(wf[6], __builtin_amdgcn_rcpf(1.f + t6), a);
                a = fmaf(wf[7], __builtin_amdgcn_rcpf(1.f + t7), a);
                acc[j] = a;
            }
        }
        __syncthreads();
    }

    float* dst = scr4 + ((size_t)eq * (BATCH * SEQ) + b * SEQ + lane) * NKEY;
    #pragma unroll
    for (int j = 0; j < 4; ++j) {
        const int n = n0 + w * 4 + j;
        if (n < NKEY) dst[n] = 2.f * acc[j];
    }
}

// ---------------------------------------------------------------------------
// attn + softmax: block = 4 s-rows x 1024 f-cols for one b. Grid (2, 16, 16).
// Softmax: row r by 64 lanes; sums 4 e-partials, applies mask, writes weights.
// ---------------------------------------------------------------------------
__global__ __launch_bounds__(256) void attn_softmax_kernel(
    const float* __restrict__ scr4, const int* __restrict__ mask,
    const float* __restrict__ feats,
    float* __restrict__ weights_out, float* __restrict__ out)
{
    const int t   = threadIdx.x;
    const int fb  = blockIdx.x;
    const int s0  = blockIdx.y * 4;
    const int b   = blockIdx.z;

    __shared__ float wt[NKEY][4];   // wt[n][s]

    const size_t SCRS = (size_t)(BATCH * SEQ) * NKEY;

    // ---- softmax: row r handled by 64 lanes ----
    {
        const int r  = t >> 6;          // 0..3
        const int ln = t & 63;
        const float* p = scr4 + (size_t)(b * SEQ + s0 + r) * NKEY;
        const int* mrow = mask + b * NKEY;
        float v[4];
        float mx = -INFINITY;
        #pragma unroll
        for (int j = 0; j < 4; ++j) {
            const int n = ln + 64 * j;
            float s = -INFINITY;
            if (n < NKEY) {
                s = p[n] + p[SCRS + n] + p[2 * SCRS + n] + p[3 * SCRS + n];
                if (mrow[n] == 0) s = -1e9f;
            }
            v[j] = s;
            mx = fmaxf(mx, s);
        }
        #pragma unroll
        for (int off = 32; off; off >>= 1) mx = fmaxf(mx, __shfl_xor(mx, off));
        float sum = 0.f;
        #pragma unroll
        for (int j = 0; j < 4; ++j) {
            v[j] = __builtin_amdgcn_exp2f((v[j] - mx) * LOG2E);
            if (ln + 64 * j < NKEY) sum += v[j];
        }
        #pragma unroll
        for (int off = 32; off; off >>= 1) sum += __shfl_xor(sum, off);
        const float inv = __builtin_amdgcn_rcpf(sum);
        float* wrow = weights_out + (size_t)(b * SEQ + s0 + r) * NKEY;
        #pragma unroll
        for (int j = 0; j < 4; ++j) {
            const int n = ln + 64 * j;
            if (n < NKEY) {
                const float wv = v[j] * inv;
                wt[n][r] = wv;
                if (fb == 0) wrow[n] = wv;
            }
        }
    }
    __syncthreads();

    // ---- attn: 1024 f-cols (float4 per thread) x 4 s-rows ----
    const int col = fb * 1024 + t * 4;
    const float* fp = feats + (size_t)b * NKEY * ATT_FEAT + col;

    float4v acc[4] = {};
    #pragma unroll 4
    for (int n = 0; n < NKEY; ++n) {
        float4v f  = *(const float4v*)(fp + (size_t)n * ATT_FEAT);
        float4v wv = *(const float4v*)&wt[n][0];   // broadcast
        acc[0] += wv.x * f;
        acc[1] += wv.y * f;
        acc[2] += wv.z * f;
        acc[3] += wv.w * f;
    }

    float* op = out + (size_t)(b * SEQ + s0) * ATT_FEAT + col;
    #pragma unroll
    for (int s = 0; s < 4; ++s)
        *(float4v*)(op + (size_t)s * ATT_FEAT) = acc[s];
}

// ---------------------------------------------------------------------------
extern "C" void kernel_launch(void* const* d_in, const int* in_sizes, int n_in,
                              void* d_out, int out_size, void* d_ws, size_t ws_size,
                              hipStream_t stream)
{
    const float* hidden = (const float*)d_in[0];
    const float* feats  = (const float*)d_in[1];
    const int*   mask   = (const int*)  d_in[2];
    const float* w_h    = (const float*)d_in[3];
    const float* w_u    = (const float*)d_in[4];
    const float* bvec   = (const float*)d_in[5];
    const float* wvec   = (const float*)d_in[6];

    float* out         = (float*)d_out;
    float* attn_out    = out;
    float* weights_out = out + (size_t)BATCH * SEQ * ATT_FEAT;

    // workspace layout (~72 MB)
    float* WhP  = (float*)d_ws;                                  // 2 x 1024x512
    float* UvP  = WhP + (size_t)2 * BATCH * SEQ * EMBED;         // 4 x 3200x512
    float* scr4 = UvP + (size_t)4 * MPAD * EMBED;                // 4 x 1024x196
    unsigned short* FAh = (unsigned short*)(scr4 + (size_t)4 * BATCH * SEQ * NKEY);
    unsigned short* FAl = FAh + (size_t)MPAD * ATT_FEAT;
    unsigned short* HAh = FAl + (size_t)MPAD * ATT_FEAT;
    unsigned short* HAl = HAh + (size_t)BATCH * SEQ * HIDDEN;
    unsigned short* UBh = HAl + (size_t)BATCH * SEQ * HIDDEN;
    unsigned short* UBl = UBh + (size_t)EMBED * ATT_FEAT;
    unsigned short* HBh = UBl + (size_t)EMBED * ATT_FEAT;
    unsigned short* HBl = HBh + (size_t)EMBED * HIDDEN;

    // 1) all preps (1120 blocks)
    uber_prep<<<dim3(1120), 256, 0, stream>>>(
        hidden, feats, w_h, w_u, HAh, HAl, FAh, FAl, HBh, HBl, UBh, UBl);

    // 2) both GEMMs k-split (464 blocks), partial outputs pre-scaled by KC
    uber_gemm<<<dim3(464), 256, 0, stream>>>(
        HAh, HAl, HBh, HBl, FAh, FAl, UBh, UBl, bvec, WhP, UvP);

    // 3) partial scores (e-quarters) -> scr4
    scores4_kernel<<<dim3((NKEY + 15) / 16, 4, BATCH), 256, 0, stream>>>(
        WhP, UvP, wvec, scr4);

    // 4) partial-sum + mask + softmax + weights write + attn
    attn_softmax_kernel<<<dim3(2, SEQ / 4, BATCH), 256, 0, stream>>>(
        scr4, mask, feats, weights_out, attn_out);
}

// Round 14
// 88.601 us; speedup vs baseline: 1.3994x; 1.1543x over previous
//
#include <hip/hip_runtime.h>
#include <math.h>

#define BATCH 16
#define SEQ 64
#define NKEY 196
#define HIDDEN 1024
#define ATT_FEAT 2048
#define EMBED 512
#define MPAD 3200          // feats rows padded to multiple of 128

using half8    = __attribute__((ext_vector_type(8))) _Float16;
using f32x4    = __attribute__((ext_vector_type(4))) float;
using f32x16   = __attribute__((ext_vector_type(16))) float;
using float4v  = __attribute__((ext_vector_type(4))) float;

#define KCONST (-2.8853900817779268f)   // -2*log2(e)
#define LOG2E  (1.4426950408889634f)

// async global->LDS, 16B per lane; dest = uniform base + lane*16
__device__ __forceinline__ void gl_lds16(const _Float16* g, _Float16* l) {
    __builtin_amdgcn_global_load_lds(
        (const __attribute__((address_space(1))) unsigned int*)g,
        (__attribute__((address_space(3))) unsigned int*)l, 16, 0, 0);
}

// ---------------------------------------------------------------------------
// Tiled f16 images: per (row-tile 128, k-tile 32): [s(2)][kh(2)][row(128)][8]
// = 4096 halves (8 KB) — exact LDS image for DMA staging + 32x32x16 frags.
// ---------------------------------------------------------------------------
__device__ inline void prep_a128(
    const float* __restrict__ A, _Float16* __restrict__ T,
    int K, int Mreal, int tm, int tk, int t)
{
    const int r  = t >> 1;
    const int hf = t & 1;
    const int grow = tm * 128 + r;
    float f[32];
    if (grow < Mreal) {
        const float* src = A + (size_t)grow * K + tk * 64 + hf * 32;
        #pragma unroll
        for (int q = 0; q < 8; ++q) {
            float4v v = *(const float4v*)(src + q * 4);
            f[q*4+0] = v.x; f[q*4+1] = v.y; f[q*4+2] = v.z; f[q*4+3] = v.w;
        }
    } else {
        #pragma unroll
        for (int j = 0; j < 32; ++j) f[j] = 0.f;
    }
    const int tkk = tk * 2 + hf;
    const size_t base = ((size_t)tm * (K >> 5) + tkk) * 4096;
    #pragma unroll
    for (int s = 0; s < 2; ++s)
        #pragma unroll
        for (int kh = 0; kh < 2; ++kh) {
            half8 h;
            #pragma unroll
            for (int j = 0; j < 8; ++j)
                h[j] = (_Float16)f[s * 16 + kh * 8 + j];
            *(half8*)(T + base + (size_t)((s * 2 + kh) * 128 + r) * 8) = h;
        }
}

__device__ inline void prep_b128(
    const float* __restrict__ W, _Float16* __restrict__ T,
    int K, int N, int tn, int tk, int t, float (*tile)[129])
{
    {
        const int kr = t >> 2;
        const int nc = (t & 3) * 32;
        const float* src = W + (size_t)(tk * 64 + kr) * N + tn * 128 + nc;
        #pragma unroll
        for (int q = 0; q < 8; ++q) {
            float4v v = *(const float4v*)(src + q * 4);
            tile[kr][nc + q*4 + 0] = v.x; tile[kr][nc + q*4 + 1] = v.y;
            tile[kr][nc + q*4 + 2] = v.z; tile[kr][nc + q*4 + 3] = v.w;
        }
    }
    __syncthreads();
    {
        const int c  = t >> 1;
        const int hf = t & 1;
        const int tkk = tk * 2 + hf;
        const size_t base = ((size_t)tn * (K >> 5) + tkk) * 4096;
        #pragma unroll
        for (int s = 0; s < 2; ++s)
            #pragma unroll
            for (int kh = 0; kh < 2; ++kh) {
                half8 h;
                #pragma unroll
                for (int j = 0; j < 8; ++j)
                    h[j] = (_Float16)tile[hf * 32 + s * 16 + kh * 8 + j][c];
                *(half8*)(T + base + (size_t)((s * 2 + kh) * 128 + c) * 8) = h;
            }
    }
}

__global__ __launch_bounds__(256) void uber_prep(
    const float* __restrict__ hidden, const float* __restrict__ feats,
    const float* __restrict__ w_h, const float* __restrict__ w_u,
    _Float16* HA, _Float16* FA, _Float16* HB, _Float16* UB)
{
    __shared__ float tile[64][129];
    const int id = blockIdx.x;
    const int t  = threadIdx.x;
    if (id < 128) {
        prep_a128(hidden, HA, HIDDEN, BATCH * SEQ, id >> 4, id & 15, t);
    } else if (id < 928) {
        const int j = id - 128;
        prep_a128(feats, FA, ATT_FEAT, BATCH * NKEY, j >> 5, j & 31, t);
    } else if (id < 992) {
        const int j = id - 928;
        prep_b128(w_h, HB, HIDDEN, EMBED, j >> 4, j & 15, t, tile);
    } else {
        const int j = id - 992;
        prep_b128(w_u, UB, ATT_FEAT, EMBED, j >> 5, j & 31, t, tile);
    }
}

// ---------------------------------------------------------------------------
// uber GEMM f16 (k-split): 128x128 tile, 4 waves 2x2, wave 64x64, BK=32,
// 16 k-steps/block, single f16 product (mfma_f32_32x32x16_f16).
//   K2 (Uv): 25rt x 4ct x 4ks = 400 blocks -> 4 f32 partials
//   K1 (Wh):  8rt x 4ct x 2ks =  64 blocks -> 2 f32 partials
// Grid 464 = 8*58 bijective XCD swizzle. 4-deep LDS buffers, counted vmcnt:
// prefetch 3 tiles ahead; waves 0,1 stage A halves, waves 2,3 stage B halves.
// Epilogue scales by KCONST; bias folded into partial 0.
// ---------------------------------------------------------------------------
__global__ __launch_bounds__(256) void uber_gemm(
    const _Float16* __restrict__ HA, const _Float16* __restrict__ HB,
    const _Float16* __restrict__ FA, const _Float16* __restrict__ UB,
    const float* __restrict__ bvec, float* __restrict__ WhP, float* __restrict__ UvP)
{
    __shared__ __align__(16) _Float16 L[2][4][4096];   // 64 KB: {A,B} x 4 bufs

    const int hh = blockIdx.x;
    const int t0 = (hh & 7) * 58 + (hh >> 3);          // bijective, G=464

    const _Float16 *Aimg, *Bimg;
    const float* bias = nullptr;
    float* C;
    int rt, ct, tk0, aK;
    if (t0 < 400) {            // K2: Uv partials
        const int ks = t0 / 100, rem = t0 % 100;
        rt = rem >> 2; ct = rem & 3;
        Aimg = FA; Bimg = UB;
        aK = ATT_FEAT >> 5; tk0 = ks * 16;
        C = UvP + (size_t)ks * MPAD * EMBED;
        if (ks == 0) bias = bvec;
    } else {                   // K1: Wh partials
        const int v = t0 - 400;
        const int ks = v >> 5, rem = v & 31;
        rt = rem >> 2; ct = rem & 3;
        Aimg = HA; Bimg = HB;
        aK = HIDDEN >> 5; tk0 = ks * 16;
        C = WhP + (size_t)ks * (BATCH * SEQ) * EMBED;
    }

    const int tid = threadIdx.x, lane = tid & 63, w = tid >> 6;
    const int wr = w >> 1, wc = w & 1;
    const int l31 = lane & 31, kh = lane >> 5;

    // staging role: waves 0,1 -> A (halves 0,1); waves 2,3 -> B (halves 0,1)
    const int isB = w >> 1;
    const int whf = w & 1;
    const _Float16* srcMat = isB ? Bimg : Aimg;
    const int majorTile = isB ? ct : rt;
    const _Float16* src0 =
        srcMat + ((size_t)majorTile * aK + tk0) * 4096 + whf * 2048 + lane * 8;

    f32x16 acc[2][2] = {};

    auto stage = [&](int buf, int t) {
        const _Float16* s = src0 + (size_t)t * 4096;
        _Float16* d = &L[isB][buf][0] + whf * 2048 + lane * 8;
        #pragma unroll
        for (int c = 0; c < 4; ++c)
            gl_lds16(s + c * 512, d + c * 512);
    };

    auto compute = [&](int buf) {
        #pragma unroll
        for (int s = 0; s < 2; ++s) {
            const int rb = (s * 2 + kh) * 128;
            half8 a[2], b[2];
            #pragma unroll
            for (int m = 0; m < 2; ++m)
                a[m] = *(const half8*)&L[0][buf][(rb + wr * 64 + m * 32 + l31) * 8];
            #pragma unroll
            for (int n = 0; n < 2; ++n)
                b[n] = *(const half8*)&L[1][buf][(rb + wc * 64 + n * 32 + l31) * 8];
            __builtin_amdgcn_s_setprio(1);
            #pragma unroll
            for (int m = 0; m < 2; ++m)
                #pragma unroll
                for (int n = 0; n < 2; ++n)
                    acc[m][n] = __builtin_amdgcn_mfma_f32_32x32x16_f16(a[m], b[n], acc[m][n], 0, 0, 0);
            __builtin_amdgcn_s_setprio(0);
        }
    };

    stage(0, 0); stage(1, 1); stage(2, 2);   // prefetch depth 3
    #pragma unroll 1
    for (int t = 0; t < 16; ++t) {
        if (t + 2 < 16)      asm volatile("s_waitcnt vmcnt(8)" ::: "memory");
        else if (t + 1 < 16) asm volatile("s_waitcnt vmcnt(4)" ::: "memory");
        else                 asm volatile("s_waitcnt vmcnt(0)" ::: "memory");
        __builtin_amdgcn_s_barrier();
        if (t + 3 < 16) stage((t + 3) & 3, t + 3);   // overwrites buf (t-1)&3: safe post-barrier
        __builtin_amdgcn_sched_barrier(0);
        compute(t & 3);
        __builtin_amdgcn_sched_barrier(0);
    }

    // epilogue: frag layout col=lane&31, row=(r&3)+8*(r>>2)+4*kh; scale by KC
    #pragma unroll
    for (int m = 0; m < 2; ++m) {
        const int row0 = rt * 128 + wr * 64 + m * 32;
        #pragma unroll
        for (int n = 0; n < 2; ++n) {
            const int colg = ct * 128 + wc * 64 + n * 32 + l31;
            const float bv = bias ? bias[colg] : 0.f;
            #pragma unroll
            for (int r = 0; r < 16; ++r) {
                const int row = (r & 3) + 8 * (r >> 2) + 4 * kh;
                C[(size_t)(row0 + row) * EMBED + colg] = (acc[m][n][r] + bv) * KCONST;
            }
        }
    }
}

// ---------------------------------------------------------------------------
// scores v3: partial scores over an e-quarter (128 e).
//   scr4[eq][b*64+s][n] = 2 * sum_{e in quarter} w[e]/(1+exp2(Wh'+Uv'))
// Block: 64 s x 16 n x 128 e, 4 waves (wave = 4 n, lane = s).
// Grid (13, 4, 16).
// ---------------------------------------------------------------------------
__global__ __launch_bounds__(256) void scores4_kernel(
    const float* __restrict__ WhP, const float* __restrict__ UvP,
    const float* __restrict__ wvec, float* __restrict__ scr4)
{
    const int n0 = blockIdx.x * 16;
    const int eq = blockIdx.y;
    const int b  = blockIdx.z;
    const int tid = threadIdx.x;
    const int w    = tid >> 6;
    const int lane = tid & 63;         // = s

    __shared__ float whs[64 * 64];     // swizzled, 16 KB
    __shared__ float uvs[16][64];      // plain (broadcast reads)

    const size_t WHS = (size_t)(BATCH * SEQ) * EMBED;
    const size_t UVS = (size_t)MPAD * EMBED;

    float acc[4] = {};
    char* whsB = (char*)whs;

    for (int ch = 0; ch < 2; ++ch) {
        const int e0 = eq * 128 + ch * 64;
        {
            const int r = tid >> 2;
            const float* Wr = WhP + (size_t)(b * SEQ + r) * EMBED + e0;
            #pragma unroll
            for (int q = 0; q < 4; ++q) {
                const int cc = (tid & 3) * 16 + q * 4;
                float4v v = *(const float4v*)(Wr + cc)
                          + *(const float4v*)(Wr + WHS + cc);
                *(float4v*)(whsB + r * 256 + ((cc * 4) ^ ((r & 15) << 4))) = v;
            }
        }
        {
            const int nl = tid >> 4;
            const int c4 = tid & 15;
            const int nr = (n0 + nl < NKEY) ? (n0 + nl) : (NKEY - 1);
            const float* Ur = UvP + (size_t)(b * NKEY + nr) * EMBED + e0 + c4 * 4;
            float4v u = *(const float4v*)(Ur)
                      + *(const float4v*)(Ur + UVS)
                      + *(const float4v*)(Ur + 2 * UVS)
                      + *(const float4v*)(Ur + 3 * UVS);
            *(float4v*)&uvs[nl][c4 * 4] = u;
        }
        __syncthreads();

        #pragma unroll
        for (int ec = 0; ec < 8; ++ec) {
            const int sb = lane * 256;
            float4v wh0 = *(const float4v*)(whsB + sb + ((ec * 32 +  0) ^ ((lane & 15) << 4)));
            float4v wh1 = *(const float4v*)(whsB + sb + ((ec * 32 + 16) ^ ((lane & 15) << 4)));
            float wf[8];
            #pragma unroll
            for (int i = 0; i < 8; ++i) wf[i] = wvec[e0 + ec * 8 + i];
            #pragma unroll
            for (int j = 0; j < 4; ++j) {
                const int nl = w * 4 + j;
                float4v u0 = *(const float4v*)&uvs[nl][ec * 8];
                float4v u1 = *(const float4v*)&uvs[nl][ec * 8 + 4];
                float t0 = __builtin_amdgcn_exp2f(wh0.x + u0.x);
                float t1 = __builtin_amdgcn_exp2f(wh0.y + u0.y);
                float t2 = __builtin_amdgcn_exp2f(wh0.z + u0.z);
                float t3 = __builtin_amdgcn_exp2f(wh0.w + u0.w);
                float t4 = __builtin_amdgcn_exp2f(wh1.x + u1.x);
                float t5 = __builtin_amdgcn_exp2f(wh1.y + u1.y);
                float t6 = __builtin_amdgcn_exp2f(wh1.z + u1.z);
                float t7 = __builtin_amdgcn_exp2f(wh1.w + u1.w);
                float a = acc[j];
                a = fmaf(wf[0], __builtin_amdgcn_rcpf(1.f + t0), a);
                a = fmaf(wf[1], __builtin_amdgcn_rcpf(1.f + t1), a);
                a = fmaf(wf[2], __builtin_amdgcn_rcpf(1.f + t2), a);
                a = fmaf(wf[3], __builtin_amdgcn_rcpf(1.f + t3), a);
                a = fmaf(wf[4], __builtin_amdgcn_rcpf(1.f + t4), a);
                a = fmaf(wf[5], __builtin_amdgcn_rcpf(1.f + t5), a);
                a = fmaf(wf[6], __builtin_amdgcn_rcpf(1.f + t6), a);
                a = fmaf(wf[7], __builtin_amdgcn_rcpf(1.f + t7), a);
                acc[j] = a;
            }
        }
        __syncthreads();
    }

    float* dst = scr4 + ((size_t)eq * (BATCH * SEQ) + b * SEQ + lane) * NKEY;
    #pragma unroll
    for (int j = 0; j < 4; ++j) {
        const int n = n0 + w * 4 + j;
        if (n < NKEY) dst[n] = 2.f * acc[j];
    }
}

// ---------------------------------------------------------------------------
// attn + softmax: block = 4 s-rows x 1024 f-cols for one b. Grid (2, 16, 16).
// ---------------------------------------------------------------------------
__global__ __launch_bounds__(256) void attn_softmax_kernel(
    const float* __restrict__ scr4, const int* __restrict__ mask,
    const float* __restrict__ feats,
    float* __restrict__ weights_out, float* __restrict__ out)
{
    const int t   = threadIdx.x;
    const int fb  = blockIdx.x;
    const int s0  = blockIdx.y * 4;
    const int b   = blockIdx.z;

    __shared__ float wt[NKEY][4];   // wt[n][s]

    const size_t SCRS = (size_t)(BATCH * SEQ) * NKEY;

    {
        const int r  = t >> 6;          // 0..3
        const int ln = t & 63;
        const float* p = scr4 + (size_t)(b * SEQ + s0 + r) * NKEY;
        const int* mrow = mask + b * NKEY;
        float v[4];
        float mx = -INFINITY;
        #pragma unroll
        for (int j = 0; j < 4; ++j) {
            const int n = ln + 64 * j;
            float s = -INFINITY;
            if (n < NKEY) {
                s = p[n] + p[SCRS + n] + p[2 * SCRS + n] + p[3 * SCRS + n];
                if (mrow[n] == 0) s = -1e9f;
            }
            v[j] = s;
            mx = fmaxf(mx, s);
        }
        #pragma unroll
        for (int off = 32; off; off >>= 1) mx = fmaxf(mx, __shfl_xor(mx, off));
        float sum = 0.f;
        #pragma unroll
        for (int j = 0; j < 4; ++j) {
            v[j] = __builtin_amdgcn_exp2f((v[j] - mx) * LOG2E);
            if (ln + 64 * j < NKEY) sum += v[j];
        }
        #pragma unroll
        for (int off = 32; off; off >>= 1) sum += __shfl_xor(sum, off);
        const float inv = __builtin_amdgcn_rcpf(sum);
        float* wrow = weights_out + (size_t)(b * SEQ + s0 + r) * NKEY;
        #pragma unroll
        for (int j = 0; j < 4; ++j) {
            const int n = ln + 64 * j;
            if (n < NKEY) {
                const float wv = v[j] * inv;
                wt[n][r] = wv;
                if (fb == 0) wrow[n] = wv;
            }
        }
    }
    __syncthreads();

    const int col = fb * 1024 + t * 4;
    const float* fp = feats + (size_t)b * NKEY * ATT_FEAT + col;

    float4v acc[4] = {};
    #pragma unroll 4
    for (int n = 0; n < NKEY; ++n) {
        float4v f  = *(const float4v*)(fp + (size_t)n * ATT_FEAT);
        float4v wv = *(const float4v*)&wt[n][0];   // broadcast
        acc[0] += wv.x * f;
        acc[1] += wv.y * f;
        acc[2] += wv.z * f;
        acc[3] += wv.w * f;
    }

    float* op = out + (size_t)(b * SEQ + s0) * ATT_FEAT + col;
    #pragma unroll
    for (int s = 0; s < 4; ++s)
        *(float4v*)(op + (size_t)s * ATT_FEAT) = acc[s];
}

// ---------------------------------------------------------------------------
extern "C" void kernel_launch(void* const* d_in, const int* in_sizes, int n_in,
                              void* d_out, int out_size, void* d_ws, size_t ws_size,
                              hipStream_t stream)
{
    const float* hidden = (const float*)d_in[0];
    const float* feats  = (const float*)d_in[1];
    const int*   mask   = (const int*)  d_in[2];
    const float* w_h    = (const float*)d_in[3];
    const float* w_u    = (const float*)d_in[4];
    const float* bvec   = (const float*)d_in[5];
    const float* wvec   = (const float*)d_in[6];

    float* out         = (float*)d_out;
    float* attn_out    = out;
    float* weights_out = out + (size_t)BATCH * SEQ * ATT_FEAT;

    // workspace layout (~52 MB)
    float* WhP  = (float*)d_ws;                                  // 2 x 1024x512
    float* UvP  = WhP + (size_t)2 * BATCH * SEQ * EMBED;         // 4 x 3200x512
    float* scr4 = UvP + (size_t)4 * MPAD * EMBED;                // 4 x 1024x196
    _Float16* FA = (_Float16*)(scr4 + (size_t)4 * BATCH * SEQ * NKEY);
    _Float16* HA = FA + (size_t)MPAD * ATT_FEAT;                 // feats img
    _Float16* UB = HA + (size_t)BATCH * SEQ * HIDDEN;            // hidden img
    _Float16* HB = UB + (size_t)EMBED * ATT_FEAT;                // w_u img
    // HB: w_h img, EMBED*HIDDEN halves

    // 1) all preps (1120 blocks), single f16 image per matrix
    uber_prep<<<dim3(1120), 256, 0, stream>>>(
        hidden, feats, w_h, w_u, HA, FA, HB, UB);

    // 2) both GEMMs k-split (464 blocks), f16 single product, scaled by KC
    uber_gemm<<<dim3(464), 256, 0, stream>>>(
        HA, HB, FA, UB, bvec, WhP, UvP);

    // 3) partial scores (e-quarters) -> scr4
    scores4_kernel<<<dim3((NKEY + 15) / 16, 4, BATCH), 256, 0, stream>>>(
        WhP, UvP, wvec, scr4);

    // 4) partial-sum + mask + softmax + weights write + attn
    attn_softmax_kernel<<<dim3(2, SEQ / 4, BATCH), 256, 0, stream>>>(
        scr4, mask, feats, weights_out, attn_out);
}